// Round 2
// baseline (354.751 us; speedup 1.0000x reference)
//
#include <hip/hip_runtime.h>
#include <hip/hip_bf16.h>
#include <math.h>

#define B_  256
#define K_  256
#define C_  128
#define C2_ 256
#define KG_ 64
#define O3_ 117
#define OD_ 183

typedef unsigned int       u32;
typedef unsigned short     u16;

__device__ __forceinline__ float bflo(u32 u) { u32 b = u << 16;        return __uint_as_float(b); }
__device__ __forceinline__ float bfhi(u32 u) { u32 b = u & 0xffff0000u; return __uint_as_float(b); }
__device__ __forceinline__ u16 f2bf(float f) {
    __hip_bfloat16 h = __float2bfloat16(f);
    return __builtin_bit_cast(u16, h);
}

// ---------------------------------------------------------------------------
// Kernel 1: objectness label = (sqrt(min_g ||xyz - gt||^2 + 1e-6) < 0.3)
// ---------------------------------------------------------------------------
__global__ __launch_bounds__(256) void objness_kernel(const float* __restrict__ xyz,
                                                      const float* __restrict__ gtc,
                                                      float* __restrict__ label)
{
    __shared__ float g[KG_ * 3];
    const int b = blockIdx.x, t = threadIdx.x;
    if (t < KG_ * 3) g[t] = gtc[(size_t)b * KG_ * 3 + t];
    __syncthreads();
    const size_t pidx = (size_t)(b * K_ + t);
    float x = xyz[pidx * 3 + 0];
    float y = xyz[pidx * 3 + 1];
    float z = xyz[pidx * 3 + 2];
    float dmin = 1e30f;
#pragma unroll 8
    for (int j = 0; j < KG_; ++j) {
        float dx = x - g[j * 3 + 0];
        float dy = y - g[j * 3 + 1];
        float dz = z - g[j * 3 + 2];
        float d  = dx * dx + dy * dy + dz * dz;
        dmin = fminf(dmin, d);
    }
    float e = sqrtf(dmin + 1e-6f);
    label[pidx] = (e < 0.3f) ? 1.0f : 0.0f;
}

// ---------------------------------------------------------------------------
// Kernel 2: get_index — stable compaction of indices with pred==1, rest = k
// ---------------------------------------------------------------------------
__global__ __launch_bounds__(256) void getindex_kernel(const int* __restrict__ pred,
                                                       float* __restrict__ idxo,
                                                       float* __restrict__ sum1)
{
    const int b = blockIdx.x, t = threadIdx.x;
    const int p = (pred[b * K_ + t] == 1) ? 1 : 0;
    __shared__ int sd[K_];
    sd[t] = p;
    __syncthreads();
    for (int off = 1; off < K_; off <<= 1) {
        int v = (t >= off) ? sd[t - off] : 0;
        __syncthreads();
        sd[t] += v;
        __syncthreads();
    }
    const int incl = sd[t];
    const int num  = sd[K_ - 1];
    if (t >= num) idxo[b * K_ + t] = (float)t;
    if (p)        idxo[b * K_ + (incl - p)] = (float)t;
    if (t == 0)   sum1[b] = (float)num;
}

// ---------------------------------------------------------------------------
// GEMM1: net1_pre[b,o,k] = sum_c W1[o,c] * feat[b,c,k] + b1[o]   (c over 256)
// feat = concat(features, rn_feature) along c. Output bf16 to workspace.
// Block: 128 o x 64 p, 256 threads, each 8o x 4p. c-tiles of 32.
// ---------------------------------------------------------------------------
__global__ __launch_bounds__(256) void gemm1_kernel(const float* __restrict__ fa,
                                                    const float* __restrict__ fb,
                                                    const float* __restrict__ W,
                                                    const float* __restrict__ bias,
                                                    u16* __restrict__ outbf)
{
    __shared__ float Wl[32][132];   // [c][o], stride 132 floats (16B aligned rows)
    __shared__ float Fl[32][68];    // [c][p]
    const int tid = threadIdx.x;
    const int blk = blockIdx.x;
    const int b   = blk >> 2;
    const int p0  = (blk & 3) << 6;
    const int to  = tid >> 4;
    const int tp  = tid & 15;

    float acc[8][4];
#pragma unroll
    for (int i = 0; i < 8; ++i)
#pragma unroll
        for (int j = 0; j < 4; ++j) acc[i][j] = 0.0f;

    const size_t basA = (size_t)b * C_ * K_;

    for (int cc = 0; cc < C2_; cc += 32) {
#pragma unroll
        for (int i = 0; i < 16; ++i) {          // 4096 W elems
            int e = tid + (i << 8);
            int o = e >> 5, c = e & 31;
            Wl[c][o] = W[o * C2_ + cc + c];
        }
        const float* src = (cc < C_) ? (fa + basA + (size_t)cc * K_)
                                     : (fb + basA + (size_t)(cc - C_) * K_);
#pragma unroll
        for (int i = 0; i < 8; ++i) {           // 2048 F elems
            int e = tid + (i << 8);
            int c = e >> 6, p = e & 63;
            Fl[c][p] = src[c * K_ + p0 + p];
        }
        __syncthreads();
#pragma unroll
        for (int c = 0; c < 32; ++c) {
            float4 f  = *(const float4*)&Fl[c][tp << 2];
            float4 w0 = *(const float4*)&Wl[c][to << 3];
            float4 w1 = *(const float4*)&Wl[c][(to << 3) + 4];
            float fv[4] = {f.x, f.y, f.z, f.w};
            float wv[8] = {w0.x, w0.y, w0.z, w0.w, w1.x, w1.y, w1.z, w1.w};
#pragma unroll
            for (int i = 0; i < 8; ++i)
#pragma unroll
                for (int j = 0; j < 4; ++j)
                    acc[i][j] = fmaf(wv[i], fv[j], acc[i][j]);
        }
        __syncthreads();
    }
#pragma unroll
    for (int i = 0; i < 8; ++i) {
        int o = (to << 3) + i;
        float bv = bias[o];
        ushort4 r;
        r.x = f2bf(acc[i][0] + bv);
        r.y = f2bf(acc[i][1] + bv);
        r.z = f2bf(acc[i][2] + bv);
        r.w = f2bf(acc[i][3] + bv);
        *(ushort4*)&outbf[((size_t)(b * C_ + o)) * K_ + p0 + (tp << 2)] = r;
    }
}

// ---------------------------------------------------------------------------
// Stats: per-channel mean/var over (B,K) of bf16 pre-activations ->
//        scale = g * rsqrt(var+eps), shift = be - mean*scale
// ---------------------------------------------------------------------------
__global__ __launch_bounds__(256) void stats_kernel(const u16* __restrict__ net,
                                                    const float* __restrict__ g,
                                                    const float* __restrict__ be,
                                                    float* __restrict__ scale,
                                                    float* __restrict__ shift)
{
    const int c = blockIdx.x;
    const int tid = threadIdx.x;
    const int half = tid >> 7;          // 0/1 -> which row of the pair
    const int u    = tid & 127;         // uint (2xbf16) index within row
    float s = 0.0f, s2 = 0.0f;
    for (int b2 = 0; b2 < B_; b2 += 2) {
        int b = b2 + half;
        const u32* p = (const u32*)(net + ((size_t)(b * C_ + c)) * K_);
        u32 v = p[u];
        float x0 = bflo(v), x1 = bfhi(v);
        s += x0 + x1;
        s2 = fmaf(x0, x0, s2);
        s2 = fmaf(x1, x1, s2);
    }
    __shared__ float rs[256], rs2[256];
    rs[tid] = s; rs2[tid] = s2;
    __syncthreads();
    for (int off = 128; off > 0; off >>= 1) {
        if (tid < off) { rs[tid] += rs[tid + off]; rs2[tid] += rs2[tid + off]; }
        __syncthreads();
    }
    if (tid == 0) {
        const float inv = 1.0f / 65536.0f;
        float mean = rs[0] * inv;
        float var  = rs2[0] * inv - mean * mean;
        float sc   = g[c] * rsqrtf(var + 1e-5f);
        scale[c] = sc;
        shift[c] = be[c] - mean * sc;
    }
}

// ---------------------------------------------------------------------------
// GEMM2: net2_pre[b,o,k] = sum_c W2[o,c]*max(0, net1[b,c,k]*s[c]+t[c]) + b2[o]
// ---------------------------------------------------------------------------
__global__ __launch_bounds__(256) void gemm2_kernel(const u16* __restrict__ inbf,
                                                    const float* __restrict__ scale,
                                                    const float* __restrict__ shift,
                                                    const float* __restrict__ W,
                                                    const float* __restrict__ bias,
                                                    u16* __restrict__ outbf)
{
    __shared__ float Wl[32][132];
    __shared__ float Fl[32][68];
    __shared__ float Sc[C_], Sh[C_];
    const int tid = threadIdx.x;
    const int blk = blockIdx.x;
    const int b   = blk >> 2;
    const int p0  = (blk & 3) << 6;
    const int to  = tid >> 4;
    const int tp  = tid & 15;

    if (tid < C_) { Sc[tid] = scale[tid]; Sh[tid] = shift[tid]; }
    __syncthreads();

    float acc[8][4];
#pragma unroll
    for (int i = 0; i < 8; ++i)
#pragma unroll
        for (int j = 0; j < 4; ++j) acc[i][j] = 0.0f;

    for (int cc = 0; cc < C_; cc += 32) {
#pragma unroll
        for (int i = 0; i < 16; ++i) {
            int e = tid + (i << 8);
            int o = e >> 5, c = e & 31;
            Wl[c][o] = W[o * C_ + cc + c];
        }
        const u32* src = (const u32*)(inbf + ((size_t)(b * C_ + cc)) * K_);
#pragma unroll
        for (int i = 0; i < 4; ++i) {           // 1024 uints = 2048 bf16
            int e = tid + (i << 8);
            int c = e >> 5, u = e & 31;
            u32 v = src[c * (K_ / 2) + (p0 >> 1) + u];
            float s = Sc[cc + c], t = Sh[cc + c];
            float x0 = fmaxf(0.0f, fmaf(bflo(v), s, t));
            float x1 = fmaxf(0.0f, fmaf(bfhi(v), s, t));
            *(float2*)&Fl[c][u << 1] = make_float2(x0, x1);
        }
        __syncthreads();
#pragma unroll
        for (int c = 0; c < 32; ++c) {
            float4 f  = *(const float4*)&Fl[c][tp << 2];
            float4 w0 = *(const float4*)&Wl[c][to << 3];
            float4 w1 = *(const float4*)&Wl[c][(to << 3) + 4];
            float fv[4] = {f.x, f.y, f.z, f.w};
            float wv[8] = {w0.x, w0.y, w0.z, w0.w, w1.x, w1.y, w1.z, w1.w};
#pragma unroll
            for (int i = 0; i < 8; ++i)
#pragma unroll
                for (int j = 0; j < 4; ++j)
                    acc[i][j] = fmaf(wv[i], fv[j], acc[i][j]);
        }
        __syncthreads();
    }
#pragma unroll
    for (int i = 0; i < 8; ++i) {
        int o = (to << 3) + i;
        float bv = bias[o];
        ushort4 r;
        r.x = f2bf(acc[i][0] + bv);
        r.y = f2bf(acc[i][1] + bv);
        r.z = f2bf(acc[i][2] + bv);
        r.w = f2bf(acc[i][3] + bv);
        *(ushort4*)&outbf[((size_t)(b * C_ + o)) * K_ + p0 + (tp << 2)] = r;
    }
}

// ---------------------------------------------------------------------------
// GEMM3: t[b,k,o] = sum_c W3[o,c]*max(0, net2[b,c,k]*s[c]+t[c]) + b3[o]
//        then scatter into the 183-wide output with xyz / pi/12 / mean_size.
// ---------------------------------------------------------------------------
__global__ __launch_bounds__(256) void gemm3_kernel(const u16* __restrict__ inbf,
                                                    const float* __restrict__ scale,
                                                    const float* __restrict__ shift,
                                                    const float* __restrict__ W,     // 117x128
                                                    const float* __restrict__ bias,  // 117
                                                    const float* __restrict__ xyz,
                                                    const float* __restrict__ msize, // 54
                                                    float* __restrict__ out)         // (B,K,183)
{
    __shared__ float Wl[32][132];
    __shared__ float Fl[32][68];
    __shared__ float Sc[C_], Sh[C_];
    __shared__ float Ms[54];
    const int tid = threadIdx.x;
    const int blk = blockIdx.x;
    const int b   = blk >> 2;
    const int p0  = (blk & 3) << 6;
    const int to  = tid >> 4;
    const int tp  = tid & 15;

    if (tid < C_) { Sc[tid] = scale[tid]; Sh[tid] = shift[tid]; }
    if (tid >= C_ && tid < C_ + 54) Ms[tid - C_] = msize[tid - C_];
    __syncthreads();

    float acc[8][4];
#pragma unroll
    for (int i = 0; i < 8; ++i)
#pragma unroll
        for (int j = 0; j < 4; ++j) acc[i][j] = 0.0f;

    for (int cc = 0; cc < C_; cc += 32) {
#pragma unroll
        for (int i = 0; i < 16; ++i) {
            int e = tid + (i << 8);
            int o = e >> 5, c = e & 31;
            Wl[c][o] = (o < O3_) ? W[o * C_ + cc + c] : 0.0f;
        }
        const u32* src = (const u32*)(inbf + ((size_t)(b * C_ + cc)) * K_);
#pragma unroll
        for (int i = 0; i < 4; ++i) {
            int e = tid + (i << 8);
            int c = e >> 5, u = e & 31;
            u32 v = src[c * (K_ / 2) + (p0 >> 1) + u];
            float s = Sc[cc + c], t = Sh[cc + c];
            float x0 = fmaxf(0.0f, fmaf(bflo(v), s, t));
            float x1 = fmaxf(0.0f, fmaf(bfhi(v), s, t));
            *(float2*)&Fl[c][u << 1] = make_float2(x0, x1);
        }
        __syncthreads();
#pragma unroll
        for (int c = 0; c < 32; ++c) {
            float4 f  = *(const float4*)&Fl[c][tp << 2];
            float4 w0 = *(const float4*)&Wl[c][to << 3];
            float4 w1 = *(const float4*)&Wl[c][(to << 3) + 4];
            float fv[4] = {f.x, f.y, f.z, f.w};
            float wv[8] = {w0.x, w0.y, w0.z, w0.w, w1.x, w1.y, w1.z, w1.w};
#pragma unroll
            for (int i = 0; i < 8; ++i)
#pragma unroll
                for (int j = 0; j < 4; ++j)
                    acc[i][j] = fmaf(wv[i], fv[j], acc[i][j]);
        }
        __syncthreads();
    }

    const float PI12 = 0.2617993877991494f;  // pi/12
#pragma unroll
    for (int i = 0; i < 8; ++i) {
        int o = (to << 3) + i;
        if (o >= O3_) continue;
        float bv = bias[o];
#pragma unroll
        for (int j = 0; j < 4; ++j) {
            int k = p0 + (tp << 2) + j;
            size_t ob = ((size_t)(b * K_ + k)) * OD_;
            float v = acc[i][j] + bv;
            if (o < 3) {
                out[ob + o] = xyz[((size_t)(b * K_ + k)) * 3 + o] + v;
            } else if (o < 15) {
                out[ob + o] = v;
            } else if (o < 27) {
                out[ob + o] = v;
                out[ob + o + 12] = v * PI12;
            } else if (o < 45) {
                out[ob + o + 12] = v;
            } else if (o < 99) {
                out[ob + o + 12] = v;
                out[ob + o + 66] = v * Ms[o - 45];
            } else {
                out[ob + o + 66] = v;
            }
        }
    }
}

// ---------------------------------------------------------------------------
extern "C" void kernel_launch(void* const* d_in, const int* in_sizes, int n_in,
                              void* d_out, int out_size, void* d_ws, size_t ws_size,
                              hipStream_t stream)
{
    const float* xyz      = (const float*)d_in[0];
    const float* features = (const float*)d_in[1];
    const float* rn       = (const float*)d_in[2];
    const float* gtc      = (const float*)d_in[3];
    const int*   pred     = (const int*)d_in[4];
    const float* W1  = (const float*)d_in[5];
    const float* b1  = (const float*)d_in[6];
    const float* g1  = (const float*)d_in[7];
    const float* be1 = (const float*)d_in[8];
    const float* W2  = (const float*)d_in[9];
    const float* b2  = (const float*)d_in[10];
    const float* g2  = (const float*)d_in[11];
    const float* be2 = (const float*)d_in[12];
    const float* W3  = (const float*)d_in[13];
    const float* b3  = (const float*)d_in[14];
    const float* ms  = (const float*)d_in[15];

    float* out = (float*)d_out;
    const size_t OFF_IDX = (size_t)B_ * K_ * OD_;
    const size_t OFF_SUM = OFF_IDX + (size_t)B_ * K_;
    const size_t OFF_LAB = OFF_SUM + B_;

    char* ws = (char*)d_ws;
    u16* net1 = (u16*)ws;                               // 16,777,216 B
    u16* net2 = (u16*)(ws + 16777216);                  // 16,777,216 B
    float* sc1 = (float*)(ws + 33554432);
    float* sh1 = sc1 + C_;
    float* sc2 = sh1 + C_;
    float* sh2 = sc2 + C_;

    objness_kernel<<<B_, 256, 0, stream>>>(xyz, gtc, out + OFF_LAB);
    getindex_kernel<<<B_, 256, 0, stream>>>(pred, out + OFF_IDX, out + OFF_SUM);
    gemm1_kernel<<<1024, 256, 0, stream>>>(features, rn, W1, b1, net1);
    stats_kernel<<<C_, 256, 0, stream>>>(net1, g1, be1, sc1, sh1);
    gemm2_kernel<<<1024, 256, 0, stream>>>(net1, sc1, sh1, W2, b2, net2);
    stats_kernel<<<C_, 256, 0, stream>>>(net2, g2, be2, sc2, sh2);
    gemm3_kernel<<<1024, 256, 0, stream>>>(net2, sc2, sh2, W3, b3, xyz, ms, out);
}

// Round 3
// 209.019 us; speedup vs baseline: 1.6972x; 1.6972x over previous
//
#include <hip/hip_runtime.h>
#include <hip/hip_bf16.h>
#include <math.h>

#define B_  256
#define K_  256
#define C_  128
#define KG_ 64
#define O3_ 117
#define OD_ 183
#define NPT 65536

typedef unsigned int  u32;
typedef unsigned short u16;
typedef __bf16 bf16_t;
typedef bf16_t bf16x8 __attribute__((ext_vector_type(8)));
typedef float  f32x4  __attribute__((ext_vector_type(4)));

__device__ __forceinline__ float bflo(u32 u){ return __uint_as_float(u << 16); }
__device__ __forceinline__ float bfhi(u32 u){ return __uint_as_float(u & 0xffff0000u); }
__device__ __forceinline__ u16 f2bf(float f){
    __hip_bfloat16 h = __float2bfloat16(f);
    return __builtin_bit_cast(u16, h);
}
// LDS row swizzle: rows are 256B; XOR bits 4-6 of byte-in-row with (row>>1)&7.
__device__ __forceinline__ int swz(int row, int byteInRow){
    return row * 256 + (byteInRow ^ (((row >> 1) & 7) << 4));
}

// ---------------------------------------------------------------------------
// prep: convert W1/W2/W3 to bf16 (W3 zero-padded to 128 rows), zero stat accums
// ---------------------------------------------------------------------------
__global__ __launch_bounds__(256) void prep_kernel(const float* __restrict__ W1,
                                                   const float* __restrict__ W2,
                                                   const float* __restrict__ W3,
                                                   u16* __restrict__ W1bf,
                                                   u16* __restrict__ W2bf,
                                                   u16* __restrict__ W3bf,
                                                   float* __restrict__ accum)
{
    int idx = blockIdx.x * 256 + threadIdx.x;
    if (idx < 512) accum[idx] = 0.0f;
    if (idx < 32768) {
        W1bf[idx] = f2bf(W1[idx]);
    } else if (idx < 49152) {
        int j = idx - 32768;
        W2bf[j] = f2bf(W2[j]);
    } else {
        int j = idx - 49152;
        int row = j >> 7, col = j & 127;
        W3bf[j] = (row < O3_) ? f2bf(W3[row * C_ + col]) : (u16)0;
    }
}

// ---------------------------------------------------------------------------
// objectness label
// ---------------------------------------------------------------------------
__global__ __launch_bounds__(256) void objness_kernel(const float* __restrict__ xyz,
                                                      const float* __restrict__ gtc,
                                                      float* __restrict__ label)
{
    __shared__ float g[KG_ * 3];
    const int b = blockIdx.x, t = threadIdx.x;
    if (t < KG_ * 3) g[t] = gtc[(size_t)b * KG_ * 3 + t];
    __syncthreads();
    const size_t pidx = (size_t)(b * K_ + t);
    float x = xyz[pidx * 3 + 0];
    float y = xyz[pidx * 3 + 1];
    float z = xyz[pidx * 3 + 2];
    float dmin = 1e30f;
#pragma unroll 8
    for (int j = 0; j < KG_; ++j) {
        float dx = x - g[j * 3 + 0];
        float dy = y - g[j * 3 + 1];
        float dz = z - g[j * 3 + 2];
        float d  = dx * dx + dy * dy + dz * dz;
        dmin = fminf(dmin, d);
    }
    float e = sqrtf(dmin + 1e-6f);
    label[pidx] = (e < 0.3f) ? 1.0f : 0.0f;
}

// ---------------------------------------------------------------------------
// get_index
// ---------------------------------------------------------------------------
__global__ __launch_bounds__(256) void getindex_kernel(const int* __restrict__ pred,
                                                       float* __restrict__ idxo,
                                                       float* __restrict__ sum1)
{
    const int b = blockIdx.x, t = threadIdx.x;
    const int p = (pred[b * K_ + t] == 1) ? 1 : 0;
    __shared__ int sd[K_];
    sd[t] = p;
    __syncthreads();
    for (int off = 1; off < K_; off <<= 1) {
        int v = (t >= off) ? sd[t - off] : 0;
        __syncthreads();
        sd[t] += v;
        __syncthreads();
    }
    const int incl = sd[t];
    const int num  = sd[K_ - 1];
    if (t >= num) idxo[b * K_ + t] = (float)t;
    if (p)        idxo[b * K_ + (incl - p)] = (float)t;
    if (t == 0)   sum1[b] = (float)num;
}

// ---------------------------------------------------------------------------
// GEMM1 (MFMA): out[pt][o] = sum_c feat[pt][c] * W1[o][c] + b1[o], bf16 out
// 128-pt x 128-o block, K=256 in two phases (features / rn_feature).
// A staged via fp32->bf16 transpose; W staged from pre-converted bf16.
// ---------------------------------------------------------------------------
__global__ __launch_bounds__(256) void gemm1_kernel(const float* __restrict__ fa,
                                                    const float* __restrict__ fb,
                                                    const u16* __restrict__ Wbf,  // [128][256]
                                                    const float* __restrict__ bias,
                                                    u16* __restrict__ outp)       // [NPT][128]
{
    __shared__ __align__(16) char smem[65536];   // As: 0..32K, Ws: 32K..64K
    const int t   = threadIdx.x;
    const int pt0 = blockIdx.x * 128;
    const int bb  = pt0 >> 8;
    const int k0  = pt0 & 255;
    const int w   = t >> 6, l = t & 63;
    const int lr  = l & 15, lg = l >> 4;

    f32x4 acc[2][8] = {};

    for (int ph = 0; ph < 2; ++ph) {
        if (ph) __syncthreads();
        const float* src = (ph == 0) ? fa : fb;
        // stage A: transpose [c][pt] fp32 -> [pt][c] bf16 (swizzled)
        {
            const int q  = t & 31;     // pt quad
            const int cb = t >> 5;     // 0..7
#pragma unroll
            for (int j = 0; j < 4; ++j) {
                int cq = cb + j * 8;   // c-quad 0..31
                float4 r0 = *(const float4*)(src + ((size_t)(bb*C_ + cq*4 + 0))*K_ + k0 + q*4);
                float4 r1 = *(const float4*)(src + ((size_t)(bb*C_ + cq*4 + 1))*K_ + k0 + q*4);
                float4 r2 = *(const float4*)(src + ((size_t)(bb*C_ + cq*4 + 2))*K_ + k0 + q*4);
                float4 r3 = *(const float4*)(src + ((size_t)(bb*C_ + cq*4 + 3))*K_ + k0 + q*4);
                const float* p0 = (const float*)&r0;
                const float* p1 = (const float*)&r1;
                const float* p2 = (const float*)&r2;
                const float* p3 = (const float*)&r3;
#pragma unroll
                for (int p = 0; p < 4; ++p) {
                    int row = q * 4 + p;
                    uint2 uv;
                    uv.x = (u32)f2bf(p0[p]) | ((u32)f2bf(p1[p]) << 16);
                    uv.y = (u32)f2bf(p2[p]) | ((u32)f2bf(p3[p]) << 16);
                    *(uint2*)(smem + swz(row, cq * 8)) = uv;
                }
            }
        }
        // stage W half: rows o 0..127, phase c-half
        {
            int c8 = (t & 15) * 8;
#pragma unroll
            for (int rr = 0; rr < 8; ++rr) {
                int row = (t >> 4) + rr * 16;
                uint4 v = *(const uint4*)(Wbf + (size_t)row * 256 + ph * 128 + c8);
                *(uint4*)(smem + 32768 + swz(row, c8 * 2)) = v;
            }
        }
        __syncthreads();
#pragma unroll
        for (int ks = 0; ks < 4; ++ks) {
            bf16x8 a[2], bfr[8];
#pragma unroll
            for (int m = 0; m < 2; ++m) {
                int row = w * 32 + m * 16 + lr;
                a[m] = *(const bf16x8*)(smem + swz(row, ks * 64 + lg * 16));
            }
#pragma unroll
            for (int n = 0; n < 8; ++n) {
                int row = n * 16 + lr;
                bfr[n] = *(const bf16x8*)(smem + 32768 + swz(row, ks * 64 + lg * 16));
            }
#pragma unroll
            for (int m = 0; m < 2; ++m)
#pragma unroll
                for (int n = 0; n < 8; ++n)
                    acc[m][n] = __builtin_amdgcn_mfma_f32_16x16x32_bf16(a[m], bfr[n], acc[m][n], 0, 0, 0);
        }
    }
    // epilogue: + bias, bf16 store (point-major)
    float bv[8];
#pragma unroll
    for (int n = 0; n < 8; ++n) bv[n] = bias[n * 16 + lr];
#pragma unroll
    for (int m = 0; m < 2; ++m)
#pragma unroll
        for (int n = 0; n < 8; ++n) {
            int o = n * 16 + lr;
#pragma unroll
            for (int r = 0; r < 4; ++r) {
                int row = pt0 + w * 32 + m * 16 + lg * 4 + r;
                outp[(size_t)row * 128 + o] = f2bf(acc[m][n][r] + bv[n]);
            }
        }
}

// ---------------------------------------------------------------------------
// stats: per-channel sum/sumsq over all 65536 points (point-major bf16 input)
// ---------------------------------------------------------------------------
__global__ __launch_bounds__(256) void stats_kernel(const u16* __restrict__ net,
                                                    float* __restrict__ sumArr,
                                                    float* __restrict__ sqArr)
{
    const int t  = threadIdx.x;
    const int o2 = t & 63;
    const int rg = t >> 6;
    const u32* p = (const u32*)net;
    float sl = 0.f, shi = 0.f, ql = 0.f, qh = 0.f;
    const int base = blockIdx.x * 512 + rg;
    for (int i = 0; i < 128; ++i) {
        u32 v = p[(size_t)(base + i * 4) * 64 + o2];
        float x0 = bflo(v), x1 = bfhi(v);
        sl += x0; shi += x1;
        ql = fmaf(x0, x0, ql); qh = fmaf(x1, x1, qh);
    }
    __shared__ float red[4][64][4];
    red[rg][o2][0] = sl; red[rg][o2][1] = shi;
    red[rg][o2][2] = ql; red[rg][o2][3] = qh;
    __syncthreads();
    if (t < 64) {
        float a0 = 0, a1 = 0, a2 = 0, a3 = 0;
#pragma unroll
        for (int r = 0; r < 4; ++r) {
            a0 += red[r][t][0]; a1 += red[r][t][1];
            a2 += red[r][t][2]; a3 += red[r][t][3];
        }
        atomicAdd(&sumArr[2 * t],     a0);
        atomicAdd(&sumArr[2 * t + 1], a1);
        atomicAdd(&sqArr[2 * t],      a2);
        atomicAdd(&sqArr[2 * t + 1],  a3);
    }
}

__global__ __launch_bounds__(128) void finalize_kernel(const float* __restrict__ sum,
                                                       const float* __restrict__ sq,
                                                       const float* __restrict__ g,
                                                       const float* __restrict__ be,
                                                       float* __restrict__ sc,
                                                       float* __restrict__ sh)
{
    int c = threadIdx.x;
    const float inv = 1.0f / 65536.0f;
    float mean = sum[c] * inv;
    float var  = sq[c] * inv - mean * mean;
    float s = g[c] * rsqrtf(var + 1e-5f);
    sc[c] = s;
    sh[c] = be[c] - mean * s;
}

// ---------------------------------------------------------------------------
// GEMM2 (MFMA): BN+ReLU applied while staging A; bf16 point-major out
// ---------------------------------------------------------------------------
__global__ __launch_bounds__(256) void gemm2_kernel(const u16* __restrict__ inp,
                                                    const float* __restrict__ sc,
                                                    const float* __restrict__ sh,
                                                    const u16* __restrict__ Wbf,  // [128][128]
                                                    const float* __restrict__ bias,
                                                    u16* __restrict__ outp)
{
    __shared__ __align__(16) char smem[65536];
    const int t   = threadIdx.x;
    const int pt0 = blockIdx.x * 128;
    const int w   = t >> 6, l = t & 63;
    const int lr  = l & 15, lg = l >> 4;

    {
        int c8 = (t & 15) * 8;
        float s0[8], t0[8];
#pragma unroll
        for (int j = 0; j < 8; ++j) { s0[j] = sc[c8 + j]; t0[j] = sh[c8 + j]; }
#pragma unroll
        for (int rr = 0; rr < 8; ++rr) {
            int row = (t >> 4) + rr * 16;
            uint4 v = *(const uint4*)(inp + (size_t)(pt0 + row) * 128 + c8);
            u32 vv[4] = {v.x, v.y, v.z, v.w};
            u32 ov[4];
#pragma unroll
            for (int k = 0; k < 4; ++k) {
                float x0 = fmaxf(0.f, fmaf(bflo(vv[k]), s0[2 * k],     t0[2 * k]));
                float x1 = fmaxf(0.f, fmaf(bfhi(vv[k]), s0[2 * k + 1], t0[2 * k + 1]));
                ov[k] = (u32)f2bf(x0) | ((u32)f2bf(x1) << 16);
            }
            uint4 q; q.x = ov[0]; q.y = ov[1]; q.z = ov[2]; q.w = ov[3];
            *(uint4*)(smem + swz(row, c8 * 2)) = q;
        }
#pragma unroll
        for (int rr = 0; rr < 8; ++rr) {
            int row = (t >> 4) + rr * 16;
            uint4 v = *(const uint4*)(Wbf + (size_t)row * 128 + c8);
            *(uint4*)(smem + 32768 + swz(row, c8 * 2)) = v;
        }
    }
    __syncthreads();

    f32x4 acc[2][8] = {};
#pragma unroll
    for (int ks = 0; ks < 4; ++ks) {
        bf16x8 a[2], bfr[8];
#pragma unroll
        for (int m = 0; m < 2; ++m) {
            int row = w * 32 + m * 16 + lr;
            a[m] = *(const bf16x8*)(smem + swz(row, ks * 64 + lg * 16));
        }
#pragma unroll
        for (int n = 0; n < 8; ++n) {
            int row = n * 16 + lr;
            bfr[n] = *(const bf16x8*)(smem + 32768 + swz(row, ks * 64 + lg * 16));
        }
#pragma unroll
        for (int m = 0; m < 2; ++m)
#pragma unroll
            for (int n = 0; n < 8; ++n)
                acc[m][n] = __builtin_amdgcn_mfma_f32_16x16x32_bf16(a[m], bfr[n], acc[m][n], 0, 0, 0);
    }

    float bv[8];
#pragma unroll
    for (int n = 0; n < 8; ++n) bv[n] = bias[n * 16 + lr];
#pragma unroll
    for (int m = 0; m < 2; ++m)
#pragma unroll
        for (int n = 0; n < 8; ++n) {
            int o = n * 16 + lr;
#pragma unroll
            for (int r = 0; r < 4; ++r) {
                int row = pt0 + w * 32 + m * 16 + lg * 4 + r;
                outp[(size_t)row * 128 + o] = f2bf(acc[m][n][r] + bv[n]);
            }
        }
}

// ---------------------------------------------------------------------------
// GEMM3 (MFMA): BN+ReLU staging, then transform-epilogue through LDS with
// fully-contiguous 46.8KB global store per block.
// ---------------------------------------------------------------------------
__global__ __launch_bounds__(256) void gemm3_kernel(const u16* __restrict__ inp,
                                                    const float* __restrict__ sc,
                                                    const float* __restrict__ sh,
                                                    const u16* __restrict__ Wbf,   // [128][128] padded
                                                    const float* __restrict__ bias,// 117
                                                    const float* __restrict__ xyz,
                                                    const float* __restrict__ msize,
                                                    float* __restrict__ out)
{
    __shared__ __align__(16) char smem[65536];
    const int t   = threadIdx.x;
    const int pt0 = blockIdx.x * 128;
    const int w   = t >> 6, l = t & 63;
    const int lr  = l & 15, lg = l >> 4;

    {
        int c8 = (t & 15) * 8;
        float s0[8], t0[8];
#pragma unroll
        for (int j = 0; j < 8; ++j) { s0[j] = sc[c8 + j]; t0[j] = sh[c8 + j]; }
#pragma unroll
        for (int rr = 0; rr < 8; ++rr) {
            int row = (t >> 4) + rr * 16;
            uint4 v = *(const uint4*)(inp + (size_t)(pt0 + row) * 128 + c8);
            u32 vv[4] = {v.x, v.y, v.z, v.w};
            u32 ov[4];
#pragma unroll
            for (int k = 0; k < 4; ++k) {
                float x0 = fmaxf(0.f, fmaf(bflo(vv[k]), s0[2 * k],     t0[2 * k]));
                float x1 = fmaxf(0.f, fmaf(bfhi(vv[k]), s0[2 * k + 1], t0[2 * k + 1]));
                ov[k] = (u32)f2bf(x0) | ((u32)f2bf(x1) << 16);
            }
            uint4 q; q.x = ov[0]; q.y = ov[1]; q.z = ov[2]; q.w = ov[3];
            *(uint4*)(smem + swz(row, c8 * 2)) = q;
        }
#pragma unroll
        for (int rr = 0; rr < 8; ++rr) {
            int row = (t >> 4) + rr * 16;
            uint4 v = *(const uint4*)(Wbf + (size_t)row * 128 + c8);
            *(uint4*)(smem + 32768 + swz(row, c8 * 2)) = v;
        }
    }
    __syncthreads();

    f32x4 acc[2][8] = {};
#pragma unroll
    for (int ks = 0; ks < 4; ++ks) {
        bf16x8 a[2], bfr[8];
#pragma unroll
        for (int m = 0; m < 2; ++m) {
            int row = w * 32 + m * 16 + lr;
            a[m] = *(const bf16x8*)(smem + swz(row, ks * 64 + lg * 16));
        }
#pragma unroll
        for (int n = 0; n < 8; ++n) {
            int row = n * 16 + lr;
            bfr[n] = *(const bf16x8*)(smem + 32768 + swz(row, ks * 64 + lg * 16));
        }
#pragma unroll
        for (int m = 0; m < 2; ++m)
#pragma unroll
            for (int n = 0; n < 8; ++n)
                acc[m][n] = __builtin_amdgcn_mfma_f32_16x16x32_bf16(a[m], bfr[n], acc[m][n], 0, 0, 0);
    }

    const float PI12 = 0.26179938779914946f;
    for (int s = 0; s < 2; ++s) {
        __syncthreads();
        if ((w >> 1) == s) {
            float* Of = (float*)smem + (w & 1) * (32 * 184);
#pragma unroll
            for (int n = 0; n < 8; ++n) {
                int o = n * 16 + lr;
                if (o < O3_) {
                    float bvn = bias[o];
                    float msv = (o >= 45 && o < 99) ? msize[o - 45] : 0.f;
#pragma unroll
                    for (int m = 0; m < 2; ++m)
#pragma unroll
                        for (int r = 0; r < 4; ++r) {
                            int pl = m * 16 + lg * 4 + r;          // 0..31
                            float v = acc[m][n][r] + bvn;
                            float* row = Of + pl * 184;
                            if (o < 3) {
                                int gp = pt0 + w * 32 + pl;
                                row[o] = v + xyz[(size_t)gp * 3 + o];
                            } else if (o < 15) {
                                row[o] = v;
                            } else if (o < 27) {
                                row[o] = v; row[o + 12] = v * PI12;
                            } else if (o < 45) {
                                row[o + 12] = v;
                            } else if (o < 99) {
                                row[o + 12] = v; row[o + 66] = v * msv;
                            } else {
                                row[o + 66] = v;
                            }
                        }
                }
            }
        }
        __syncthreads();
        float* Ob = out + (size_t)(pt0 + s * 64) * OD_;
        const float* Sf = (const float*)smem;
        for (int i = t; i < 64 * OD_; i += 256) {
            int pl  = (int)(((u32)i * 91680u) >> 24);   // i / 183
            int col = i - pl * 183;
            Ob[i] = Sf[(pl >> 5) * (32 * 184) + (pl & 31) * 184 + col];
        }
    }
}

// ---------------------------------------------------------------------------
extern "C" void kernel_launch(void* const* d_in, const int* in_sizes, int n_in,
                              void* d_out, int out_size, void* d_ws, size_t ws_size,
                              hipStream_t stream)
{
    const float* xyz      = (const float*)d_in[0];
    const float* features = (const float*)d_in[1];
    const float* rn       = (const float*)d_in[2];
    const float* gtc      = (const float*)d_in[3];
    const int*   pred     = (const int*)d_in[4];
    const float* W1  = (const float*)d_in[5];
    const float* b1  = (const float*)d_in[6];
    const float* g1  = (const float*)d_in[7];
    const float* be1 = (const float*)d_in[8];
    const float* W2  = (const float*)d_in[9];
    const float* b2  = (const float*)d_in[10];
    const float* g2  = (const float*)d_in[11];
    const float* be2 = (const float*)d_in[12];
    const float* W3  = (const float*)d_in[13];
    const float* b3  = (const float*)d_in[14];
    const float* ms  = (const float*)d_in[15];

    float* out = (float*)d_out;
    const size_t OFF_IDX = (size_t)B_ * K_ * OD_;
    const size_t OFF_SUM = OFF_IDX + (size_t)B_ * K_;
    const size_t OFF_LAB = OFF_SUM + B_;

    char* ws = (char*)d_ws;
    u16*  net1 = (u16*)ws;                        // 16 MB  [65536][128] bf16
    u16*  net2 = (u16*)(ws + 16777216);           // 16 MB
    u16*  W1bf = (u16*)(ws + 33554432);           // 64 KB
    u16*  W2bf = (u16*)(ws + 33619968);           // 32 KB
    u16*  W3bf = (u16*)(ws + 33652736);           // 32 KB (padded 128x128)
    float* accb = (float*)(ws + 33685504);
    float* sum1 = accb;          float* sq1 = accb + 128;
    float* sum2 = accb + 256;    float* sq2 = accb + 384;
    float* sc1  = accb + 512;    float* sh1 = accb + 640;
    float* sc2  = accb + 768;    float* sh2 = accb + 896;

    prep_kernel<<<256, 256, 0, stream>>>(W1, W2, W3, W1bf, W2bf, W3bf, accb);
    objness_kernel<<<B_, 256, 0, stream>>>(xyz, gtc, out + OFF_LAB);
    getindex_kernel<<<B_, 256, 0, stream>>>(pred, out + OFF_IDX, out + OFF_SUM);

    gemm1_kernel<<<512, 256, 0, stream>>>(features, rn, W1bf, b1, net1);
    stats_kernel<<<128, 256, 0, stream>>>(net1, sum1, sq1);
    finalize_kernel<<<1, 128, 0, stream>>>(sum1, sq1, g1, be1, sc1, sh1);

    gemm2_kernel<<<512, 256, 0, stream>>>(net1, sc1, sh1, W2bf, b2, net2);
    stats_kernel<<<128, 256, 0, stream>>>(net2, sum2, sq2);
    finalize_kernel<<<1, 128, 0, stream>>>(sum2, sq2, g2, be2, sc2, sh2);

    gemm3_kernel<<<512, 256, 0, stream>>>(net2, sc2, sh2, W3bf, b3, xyz, ms, out);
}

// Round 5
// 183.905 us; speedup vs baseline: 1.9290x; 1.1366x over previous
//
#include <hip/hip_runtime.h>
#include <hip/hip_bf16.h>
#include <math.h>

#define B_  256
#define K_  256
#define C_  128
#define KG_ 64
#define O3_ 117
#define OD_ 183

typedef unsigned int  u32;
typedef unsigned short u16;
typedef __bf16 bf16_t;
typedef bf16_t bf16x8 __attribute__((ext_vector_type(8)));
typedef float  f32x4  __attribute__((ext_vector_type(4)));

__device__ __forceinline__ float bflo(u32 u){ return __uint_as_float(u << 16); }
__device__ __forceinline__ float bfhi(u32 u){ return __uint_as_float(u & 0xffff0000u); }
__device__ __forceinline__ u16 f2bf(float f){
    __hip_bfloat16 h = __float2bfloat16(f);
    return __builtin_bit_cast(u16, h);
}
// LDS row swizzle for [pt][c] MFMA tiles: rows 256B; XOR bits 4-6 with (row>>1)&7.
__device__ __forceinline__ int swz(int row, int byteInRow){
    return row * 256 + (byteInRow ^ (((row >> 1) & 7) << 4));
}

// ---------------------------------------------------------------------------
// misc: blocks 0..255 objness, 256..511 getindex, 512..767 weight-convert
// ---------------------------------------------------------------------------
__global__ __launch_bounds__(256) void misc_kernel(const float* __restrict__ xyz,
                                                   const float* __restrict__ gtc,
                                                   const int*   __restrict__ pred,
                                                   const float* __restrict__ W1,
                                                   const float* __restrict__ W2,
                                                   const float* __restrict__ W3,
                                                   u16* __restrict__ W1bf,
                                                   u16* __restrict__ W2bf,
                                                   u16* __restrict__ W3bf,
                                                   float* __restrict__ label,
                                                   float* __restrict__ idxo,
                                                   float* __restrict__ sum1)
{
    const int blk = blockIdx.x, t = threadIdx.x;
    if (blk < 256) {
        __shared__ float g[KG_ * 3];
        const int b = blk;
        if (t < KG_ * 3) g[t] = gtc[(size_t)b * KG_ * 3 + t];
        __syncthreads();
        const size_t pidx = (size_t)(b * K_ + t);
        float x = xyz[pidx * 3 + 0];
        float y = xyz[pidx * 3 + 1];
        float z = xyz[pidx * 3 + 2];
        float dmin = 1e30f;
#pragma unroll 8
        for (int j = 0; j < KG_; ++j) {
            float dx = x - g[j * 3 + 0];
            float dy = y - g[j * 3 + 1];
            float dz = z - g[j * 3 + 2];
            float d  = dx * dx + dy * dy + dz * dz;
            dmin = fminf(dmin, d);
        }
        float e = sqrtf(dmin + 1e-6f);
        label[pidx] = (e < 0.3f) ? 1.0f : 0.0f;
    } else if (blk < 512) {
        const int b = blk - 256;
        const int p = (pred[b * K_ + t] == 1) ? 1 : 0;
        __shared__ int sd[K_];
        sd[t] = p;
        __syncthreads();
        for (int off = 1; off < K_; off <<= 1) {
            int v = (t >= off) ? sd[t - off] : 0;
            __syncthreads();
            sd[t] += v;
            __syncthreads();
        }
        const int incl = sd[t];
        const int num  = sd[K_ - 1];
        if (t >= num) idxo[b * K_ + t] = (float)t;
        if (p)        idxo[b * K_ + (incl - p)] = (float)t;
        if (t == 0)   sum1[b] = (float)num;
    } else {
        int idx = (blk - 512) * 256 + t;
        if (idx < 32768) {
            W1bf[idx] = f2bf(W1[idx]);
        } else if (idx < 49152) {
            int j = idx - 32768;
            W2bf[j] = f2bf(W2[j]);
        } else {
            int j = idx - 49152;
            int row = j >> 7, col = j & 127;
            W3bf[j] = (row < O3_) ? f2bf(W3[row * C_ + col]) : (u16)0;
        }
    }
}

// ---------------------------------------------------------------------------
// shared epilogue: acc(+bias) -> LDS [c][pt] image (264B stride) + stats
// partials -> coalesced blocked store [pb][128c][128pt] + per-block partial.
// ---------------------------------------------------------------------------
__device__ __forceinline__ void epilogue_store(char* smem, const f32x4 acc[2][8],
                                               const float* __restrict__ bias,
                                               u16* __restrict__ outp, float* __restrict__ part,
                                               int pb, int t, int w, int lr, int lg)
{
    float* SP = (float*)(smem + 40960);   // [16][128]
    float* SQ = (float*)(smem + 49152);   // [16][128]
#pragma unroll
    for (int n = 0; n < 8; ++n) {
        int o = n * 16 + lr;
        float bvn = bias[o];
        float s = 0.f, q = 0.f;
#pragma unroll
        for (int m = 0; m < 2; ++m) {
            float v0 = acc[m][n][0] + bvn;
            float v1 = acc[m][n][1] + bvn;
            float v2 = acc[m][n][2] + bvn;
            float v3 = acc[m][n][3] + bvn;
            s += (v0 + v1) + (v2 + v3);
            q = fmaf(v0, v0, q); q = fmaf(v1, v1, q);
            q = fmaf(v2, v2, q); q = fmaf(v3, v3, q);
            uint2 pk;
            pk.x = (u32)f2bf(v0) | ((u32)f2bf(v1) << 16);
            pk.y = (u32)f2bf(v2) | ((u32)f2bf(v3) << 16);
            *(uint2*)(smem + o * 264 + (w * 32 + m * 16 + lg * 4) * 2) = pk;
        }
        SP[(w * 4 + lg) * 128 + o] = s;
        SQ[(w * 4 + lg) * 128 + o] = q;
    }
    __syncthreads();
    u16* dst = outp + (size_t)pb * 16384;
#pragma unroll
    for (int j = 0; j < 8; ++j) {
        int i = t + j * 256;
        int c = i >> 4, col = i & 15;
        uint4 v = *(const uint4*)(smem + c * 264 + col * 16);
        *(uint4*)(dst + c * 128 + col * 8) = v;
    }
    if (t < 128) {
        float s = 0.f, q = 0.f;
#pragma unroll
        for (int i = 0; i < 16; ++i) { s += SP[i * 128 + t]; q += SQ[i * 128 + t]; }
        part[pb * 256 + t] = s;
        part[pb * 256 + 128 + t] = q;
    }
}

// ---------------------------------------------------------------------------
// shared A-staging for gemm2/3: blocked bf16 tile -> BN+ReLU -> swizzled LDS
// ---------------------------------------------------------------------------
__device__ __forceinline__ void stage_bn(char* smem, const u16* __restrict__ net,
                                         const float* __restrict__ sc,
                                         const float* __restrict__ sh, int pb, int t)
{
    const u16* tile = net + (size_t)pb * 16384;
    const int q = t & 15, cb = t >> 4;
#pragma unroll
    for (int j = 0; j < 2; ++j) {
        int c0 = j * 64 + cb * 4;
        u32 R[4][4];
#pragma unroll
        for (int i2 = 0; i2 < 4; ++i2) {
            uint4 v = *(const uint4*)(tile + (c0 + i2) * 128 + q * 8);
            R[i2][0] = v.x; R[i2][1] = v.y; R[i2][2] = v.z; R[i2][3] = v.w;
        }
        float ss[4], tt[4];
#pragma unroll
        for (int i2 = 0; i2 < 4; ++i2) { ss[i2] = sc[c0 + i2]; tt[i2] = sh[c0 + i2]; }
#pragma unroll
        for (int p = 0; p < 8; ++p) {
            int wi = p >> 1;
            float f0, f1, f2, f3;
            if (p & 1) {
                f0 = bfhi(R[0][wi]); f1 = bfhi(R[1][wi]);
                f2 = bfhi(R[2][wi]); f3 = bfhi(R[3][wi]);
            } else {
                f0 = bflo(R[0][wi]); f1 = bflo(R[1][wi]);
                f2 = bflo(R[2][wi]); f3 = bflo(R[3][wi]);
            }
            f0 = fmaxf(0.f, fmaf(f0, ss[0], tt[0]));
            f1 = fmaxf(0.f, fmaf(f1, ss[1], tt[1]));
            f2 = fmaxf(0.f, fmaf(f2, ss[2], tt[2]));
            f3 = fmaxf(0.f, fmaf(f3, ss[3], tt[3]));
            uint2 pk;
            pk.x = (u32)f2bf(f0) | ((u32)f2bf(f1) << 16);
            pk.y = (u32)f2bf(f2) | ((u32)f2bf(f3) << 16);
            int row = q * 8 + p;
            *(uint2*)(smem + swz(row, c0 * 2)) = pk;
        }
    }
}

__device__ __forceinline__ void stage_w128(char* smem, const u16* __restrict__ Wbf, int t)
{
    int c8 = (t & 15) * 8;
#pragma unroll
    for (int rr = 0; rr < 8; ++rr) {
        int row = (t >> 4) + rr * 16;
        uint4 v = *(const uint4*)(Wbf + (size_t)row * 128 + c8);
        *(uint4*)(smem + 32768 + swz(row, c8 * 2)) = v;
    }
}

__device__ __forceinline__ void compute_tile(char* smem, f32x4 acc[2][8], int w, int lr, int lg)
{
#pragma unroll
    for (int ks = 0; ks < 4; ++ks) {
        bf16x8 a[2], bfr[8];
#pragma unroll
        for (int m = 0; m < 2; ++m) {
            int row = w * 32 + m * 16 + lr;
            a[m] = *(const bf16x8*)(smem + swz(row, ks * 64 + lg * 16));
        }
#pragma unroll
        for (int n = 0; n < 8; ++n) {
            int row = n * 16 + lr;
            bfr[n] = *(const bf16x8*)(smem + 32768 + swz(row, ks * 64 + lg * 16));
        }
#pragma unroll
        for (int m = 0; m < 2; ++m)
#pragma unroll
            for (int n = 0; n < 8; ++n)
                acc[m][n] = __builtin_amdgcn_mfma_f32_16x16x32_bf16(a[m], bfr[n], acc[m][n], 0, 0, 0);
    }
}

// ---------------------------------------------------------------------------
// GEMM1: fp32 [c][k] inputs (features | rn) -> MFMA -> blocked bf16 + partials
// ---------------------------------------------------------------------------
__global__ __launch_bounds__(256) void gemm1_kernel(const float* __restrict__ fa,
                                                    const float* __restrict__ fb,
                                                    const u16* __restrict__ Wbf,  // [128][256]
                                                    const float* __restrict__ bias,
                                                    u16* __restrict__ outp,
                                                    float* __restrict__ part)
{
    __shared__ __align__(16) char smem[65536];
    const int t   = threadIdx.x;
    const int pb  = blockIdx.x;
    const int pt0 = pb * 128;
    const int bb  = pt0 >> 8;
    const int k0  = pt0 & 255;
    const int w   = t >> 6, l = t & 63;
    const int lr  = l & 15, lg = l >> 4;

    f32x4 acc[2][8] = {};

    for (int ph = 0; ph < 2; ++ph) {
        if (ph) __syncthreads();
        const float* src = (ph == 0) ? fa : fb;
        {   // stage A: transpose [c][pt] fp32 -> [pt][c] bf16 (swizzled)
            const int q  = t & 31;
            const int cb = t >> 5;
#pragma unroll
            for (int j = 0; j < 4; ++j) {
                int cq = cb + j * 8;
                float4 r0 = *(const float4*)(src + ((size_t)(bb*C_ + cq*4 + 0))*K_ + k0 + q*4);
                float4 r1 = *(const float4*)(src + ((size_t)(bb*C_ + cq*4 + 1))*K_ + k0 + q*4);
                float4 r2 = *(const float4*)(src + ((size_t)(bb*C_ + cq*4 + 2))*K_ + k0 + q*4);
                float4 r3 = *(const float4*)(src + ((size_t)(bb*C_ + cq*4 + 3))*K_ + k0 + q*4);
                const float* p0 = (const float*)&r0;
                const float* p1 = (const float*)&r1;
                const float* p2 = (const float*)&r2;
                const float* p3 = (const float*)&r3;
#pragma unroll
                for (int p = 0; p < 4; ++p) {
                    int row = q * 4 + p;
                    uint2 uv;
                    uv.x = (u32)f2bf(p0[p]) | ((u32)f2bf(p1[p]) << 16);
                    uv.y = (u32)f2bf(p2[p]) | ((u32)f2bf(p3[p]) << 16);
                    *(uint2*)(smem + swz(row, cq * 8)) = uv;
                }
            }
        }
        {   // stage W phase-half
            int c8 = (t & 15) * 8;
#pragma unroll
            for (int rr = 0; rr < 8; ++rr) {
                int row = (t >> 4) + rr * 16;
                uint4 v = *(const uint4*)(Wbf + (size_t)row * 256 + ph * 128 + c8);
                *(uint4*)(smem + 32768 + swz(row, c8 * 2)) = v;
            }
        }
        __syncthreads();
        compute_tile(smem, acc, w, lr, lg);
    }
    __syncthreads();
    epilogue_store(smem, acc, bias, outp, part, pb, t, w, lr, lg);
}

// ---------------------------------------------------------------------------
// finalize: reduce 512 block-partials -> scale/shift
// ---------------------------------------------------------------------------
__global__ __launch_bounds__(64) void finalize_kernel(const float* __restrict__ part,
                                                      const float* __restrict__ g,
                                                      const float* __restrict__ be,
                                                      float* __restrict__ sc,
                                                      float* __restrict__ sh)
{
    const int c = blockIdx.x, l = threadIdx.x;
    float s = 0.f, q = 0.f;
#pragma unroll
    for (int i = 0; i < 8; ++i) {
        int pb = l + i * 64;
        s += part[pb * 256 + c];
        q += part[pb * 256 + 128 + c];
    }
#pragma unroll
    for (int off = 32; off > 0; off >>= 1) {
        s += __shfl_down(s, off);
        q += __shfl_down(q, off);
    }
    if (l == 0) {
        const float inv = 1.0f / 65536.0f;
        float mean = s * inv;
        float var  = q * inv - mean * mean;
        float scv  = g[c] * rsqrtf(var + 1e-5f);
        sc[c] = scv;
        sh[c] = be[c] - mean * scv;
    }
}

// ---------------------------------------------------------------------------
// GEMM2: blocked bf16 in (BN+ReLU on stage) -> blocked bf16 out + partials
// ---------------------------------------------------------------------------
__global__ __launch_bounds__(256) void gemm2_kernel(const u16* __restrict__ net,
                                                    const float* __restrict__ sc,
                                                    const float* __restrict__ sh,
                                                    const u16* __restrict__ Wbf,
                                                    const float* __restrict__ bias,
                                                    u16* __restrict__ outp,
                                                    float* __restrict__ part)
{
    __shared__ __align__(16) char smem[65536];
    const int t  = threadIdx.x;
    const int pb = blockIdx.x;
    const int w  = t >> 6, l = t & 63;
    const int lr = l & 15, lg = l >> 4;

    stage_bn(smem, net, sc, sh, pb, t);
    stage_w128(smem, Wbf, t);
    __syncthreads();

    f32x4 acc[2][8] = {};
    compute_tile(smem, acc, w, lr, lg);
    __syncthreads();
    epilogue_store(smem, acc, bias, outp, part, pb, t, w, lr, lg);
}

// ---------------------------------------------------------------------------
// GEMM3: blocked bf16 in -> transform epilogue -> contiguous fp32 out
// ---------------------------------------------------------------------------
__global__ __launch_bounds__(256) void gemm3_kernel(const u16* __restrict__ net,
                                                    const float* __restrict__ sc,
                                                    const float* __restrict__ sh,
                                                    const u16* __restrict__ Wbf,
                                                    const float* __restrict__ bias,
                                                    const float* __restrict__ xyz,
                                                    const float* __restrict__ msize,
                                                    float* __restrict__ out)
{
    __shared__ __align__(16) char smem[65536];
    const int t   = threadIdx.x;
    const int pb  = blockIdx.x;
    const int pt0 = pb * 128;
    const int w   = t >> 6, l = t & 63;
    const int lr  = l & 15, lg = l >> 4;

    stage_bn(smem, net, sc, sh, pb, t);
    stage_w128(smem, Wbf, t);
    __syncthreads();

    f32x4 acc[2][8] = {};
    compute_tile(smem, acc, w, lr, lg);

    const float PI12 = 0.26179938779914946f;
    for (int s = 0; s < 2; ++s) {
        __syncthreads();
        if ((w >> 1) == s) {
            float* Of = (float*)smem + (w & 1) * (32 * 184);
#pragma unroll
            for (int n = 0; n < 8; ++n) {
                int o = n * 16 + lr;
                if (o < O3_) {
                    float bvn = bias[o];
                    float msv = (o >= 45 && o < 99) ? msize[o - 45] : 0.f;
#pragma unroll
                    for (int m = 0; m < 2; ++m)
#pragma unroll
                        for (int r = 0; r < 4; ++r) {
                            int pl = m * 16 + lg * 4 + r;
                            float v = acc[m][n][r] + bvn;
                            float* row = Of + pl * 184;
                            if (o < 3) {
                                int gp = pt0 + w * 32 + pl;
                                row[o] = v + xyz[(size_t)gp * 3 + o];
                            } else if (o < 15) {
                                row[o] = v;
                            } else if (o < 27) {
                                row[o] = v; row[o + 12] = v * PI12;
                            } else if (o < 45) {
                                row[o + 12] = v;
                            } else if (o < 99) {
                                row[o + 12] = v; row[o + 66] = v * msv;
                            } else {
                                row[o + 66] = v;
                            }
                        }
                }
            }
        }
        __syncthreads();
        float* Ob = out + (size_t)(pt0 + s * 64) * OD_;
        const float* Sf = (const float*)smem;
        for (int i = t; i < 64 * OD_; i += 256) {
            int pl  = (int)(((u32)i * 91680u) >> 24);   // i / 183
            int col = i - pl * 183;
            Ob[i] = Sf[(pl >> 5) * (32 * 184) + (pl & 31) * 184 + col];
        }
    }
}

// ---------------------------------------------------------------------------
extern "C" void kernel_launch(void* const* d_in, const int* in_sizes, int n_in,
                              void* d_out, int out_size, void* d_ws, size_t ws_size,
                              hipStream_t stream)
{
    const float* xyz      = (const float*)d_in[0];
    const float* features = (const float*)d_in[1];
    const float* rn       = (const float*)d_in[2];
    const float* gtc      = (const float*)d_in[3];
    const int*   pred     = (const int*)d_in[4];
    const float* W1  = (const float*)d_in[5];
    const float* b1  = (const float*)d_in[6];
    const float* g1  = (const float*)d_in[7];
    const float* be1 = (const float*)d_in[8];
    const float* W2  = (const float*)d_in[9];
    const float* b2  = (const float*)d_in[10];
    const float* g2  = (const float*)d_in[11];
    const float* be2 = (const float*)d_in[12];
    const float* W3  = (const float*)d_in[13];
    const float* b3  = (const float*)d_in[14];
    const float* ms  = (const float*)d_in[15];

    float* out = (float*)d_out;
    const size_t OFF_IDX = (size_t)B_ * K_ * OD_;
    const size_t OFF_SUM = OFF_IDX + (size_t)B_ * K_;
    const size_t OFF_LAB = OFF_SUM + B_;

    char* ws = (char*)d_ws;
    u16*  net1 = (u16*)ws;                            // 16 MB blocked [512][128][128]
    u16*  net2 = (u16*)(ws + 16777216);               // 16 MB
    u16*  W1bf = (u16*)(ws + 33554432);               // 64 KB
    u16*  W2bf = (u16*)(ws + 33619968);               // 32 KB
    u16*  W3bf = (u16*)(ws + 33652736);               // 32 KB (padded 128x128)
    float* part1 = (float*)(ws + 33685504);           // 512 KB
    float* part2 = (float*)(ws + 34209792);           // 512 KB
    float* coef  = (float*)(ws + 34734080);
    float* sc1 = coef;        float* sh1 = coef + 128;
    float* sc2 = coef + 256;  float* sh2 = coef + 384;

    misc_kernel<<<768, 256, 0, stream>>>(xyz, gtc, pred, W1, W2, W3,
                                         W1bf, W2bf, W3bf,
                                         out + OFF_LAB, out + OFF_IDX, out + OFF_SUM);

    gemm1_kernel<<<512, 256, 0, stream>>>(features, rn, W1bf, b1, net1, part1);
    finalize_kernel<<<128, 64, 0, stream>>>(part1, g1, be1, sc1, sh1);

    gemm2_kernel<<<512, 256, 0, stream>>>(net1, sc1, sh1, W2bf, b2, net2, part2);
    finalize_kernel<<<128, 64, 0, stream>>>(part2, g2, be2, sc2, sh2);

    gemm3_kernel<<<512, 256, 0, stream>>>(net2, sc2, sh2, W3bf, b3, xyz, ms, out);
}